// Round 1
// baseline (1282.091 us; speedup 1.0000x reference)
//
#include <hip/hip_runtime.h>
#include <hip/hip_bf16.h>

// out[t, j] = W[j, w[t]] + b[j]   (t in [0, 32768), j in [0, 8192))
// Strategy: bucket tokens by column-tile of W, then fused transpose+gather:
// each block loads a 64x64 tile of W coalesced into LDS and emits coalesced
// 256B row-chunks of the output for every token whose index hits this tile.

constexpr int N     = 8192;       // W is N x N
constexpr int TILE  = 64;         // tile dim (columns per bucket, rows per block)
constexpr int NBKT  = N / TILE;   // 128 buckets / column tiles

__global__ void init_k(int* counts_and_cursors) {
    // zero counts[128] + cursors[128]
    int t = threadIdx.x;
    if (t < 2 * NBKT) counts_and_cursors[t] = 0;
}

__global__ void count_k(const int* __restrict__ w, int* __restrict__ counts, int n) {
    int t = blockIdx.x * blockDim.x + threadIdx.x;
    if (t < n) atomicAdd(&counts[w[t] >> 6], 1);
}

__global__ void scan_k(const int* __restrict__ counts, int* __restrict__ offsets) {
    if (threadIdx.x == 0) {
        int acc = 0;
        for (int i = 0; i < NBKT; ++i) { offsets[i] = acc; acc += counts[i]; }
        offsets[NBKT] = acc;
    }
}

__global__ void scatter_k(const int* __restrict__ w, const int* __restrict__ offsets,
                          int* __restrict__ cursors, int* __restrict__ sorted, int n) {
    int t = blockIdx.x * blockDim.x + threadIdx.x;
    if (t < n) {
        int i   = w[t];
        int bkt = i >> 6;
        int pos = atomicAdd(&cursors[bkt], 1);
        // pack token id (15b) and in-tile column (6b): one load in the hot loop
        sorted[offsets[bkt] + pos] = (t << 6) | (i & 63);
    }
}

__global__ __launch_bounds__(256) void gather_k(const float* __restrict__ W,
                                                const float* __restrict__ b,
                                                const int* __restrict__ offsets,
                                                const int* __restrict__ sorted,
                                                float* __restrict__ out) {
    __shared__ float tile[TILE][TILE + 1];   // +1 pad: column read = 2-way (free)

    const int ct = blockIdx.x;               // column tile (= bucket)
    const int rt = blockIdx.y;               // row tile
    const int i0 = ct * TILE;
    const int j0 = rt * TILE;
    const int tid = threadIdx.x;

    // Load W[j0:j0+64, i0:i0+64] coalesced: 16 lanes x float4 per row,
    // 256 threads cover 16 rows per pass, 4 passes.
    {
        const int jr = tid >> 4;             // 0..15
        const int c4 = (tid & 15) << 2;      // 0..60
        #pragma unroll
        for (int r = 0; r < TILE; r += 16) {
            const int j = r + jr;
            const float4 v = *reinterpret_cast<const float4*>(
                &W[(size_t)(j0 + j) * N + i0 + c4]);
            tile[j][c4 + 0] = v.x;
            tile[j][c4 + 1] = v.y;
            tile[j][c4 + 2] = v.z;
            tile[j][c4 + 3] = v.w;
        }
    }
    const int lane = tid & 63;
    const int wave = tid >> 6;               // 0..3
    const float bv = b[j0 + lane];
    __syncthreads();

    const int beg = offsets[ct];
    const int end = offsets[ct + 1];
    // one wave per token per iteration; 64 lanes write 256 contiguous bytes
    for (int k = beg + wave; k < end; k += 4) {
        const int v  = sorted[k];
        const int t  = v >> 6;
        const int ii = v & 63;
        out[(size_t)t * N + j0 + lane] = tile[lane][ii] + bv;
    }
}

extern "C" void kernel_launch(void* const* d_in, const int* in_sizes, int n_in,
                              void* d_out, int out_size, void* d_ws, size_t ws_size,
                              hipStream_t stream) {
    const int*   w  = (const int*)d_in[0];      // [512*64] indices
    const float* Wm = (const float*)d_in[1];    // [8192, 8192]
    const float* b  = (const float*)d_in[2];    // [8192]
    float* out = (float*)d_out;                 // [512*64, 8192]
    const int n = in_sizes[0];                  // 32768 tokens

    int* counts  = (int*)d_ws;                  // [128]
    int* cursors = counts  + NBKT;              // [128]
    int* offsets = cursors + NBKT;              // [129]
    int* sorted  = offsets + NBKT + 1;          // [n]

    init_k<<<1, 256, 0, stream>>>(counts);
    count_k<<<(n + 255) / 256, 256, 0, stream>>>(w, counts, n);
    scan_k<<<1, 64, 0, stream>>>(counts, offsets);
    scatter_k<<<(n + 255) / 256, 256, 0, stream>>>(w, offsets, cursors, sorted, n);

    dim3 grid(NBKT, N / TILE);                  // 128 x 128 blocks
    gather_k<<<grid, 256, 0, stream>>>(Wm, b, offsets, sorted, out);
}